// Round 14
// baseline (569.542 us; speedup 1.0000x reference)
//
#include <hip/hip_runtime.h>
#include <hip/hip_bf16.h>
#include <hip/hip_cooperative_groups.h>

namespace cg = cooperative_groups;

#define NNODES   524288
#define NGRAPHS  4096
#define HG       4     // head: graphs per block-chunk
#define GS       12    // head LDS row stride (floats), 16B-aligned rows
#define FGRID    1024  // fused grid: 4 blocks/CU guaranteed by (256,4)

typedef __attribute__((ext_vector_type(8)))  short short8;
typedef __attribute__((ext_vector_type(4)))  float f32x4;
typedef __attribute__((ext_vector_type(16))) float f32x16;

static __device__ __forceinline__ unsigned short f2bf(float f) {
    __hip_bfloat16 h = __float2bfloat16(f);
    return *reinterpret_cast<unsigned short*>(&h);
}

// swizzled LDS offset (shorts): node-row 128 shorts, 16B chunks XOR-permuted
static __device__ __forceinline__ int swz(int node, int chunk) {
    return node * 128 + ((chunk ^ (node & 15)) << 3);
}

// ================= shared device bodies (used by fused + fallback) ==========

static __device__ __forceinline__ void prep_body(
        int e,
        const float* __restrict__ w0, const float* __restrict__ b0,
        const float* __restrict__ w1,
        const float* __restrict__ w2, const float* __restrict__ fw0,
        const float* __restrict__ b2,
        unsigned short* __restrict__ w0F, unsigned short* __restrict__ w1F,
        float* __restrict__ W0p, float* __restrict__ c0p,
        float* __restrict__ Pz) {
    if (e < 132096)                                     // P (2MB) + cnts (16KB)
        reinterpret_cast<float4*>(Pz)[e] = make_float4(0.f, 0.f, 0.f, 0.f);
    if (e < 16384) {
        // w1F: of = q*32+(lane&31), k = ks*16+(lane>>5)*8+j
        const int j = e & 7, lane = (e >> 3) & 63, ks = (e >> 9) & 7, q = (e >> 12) & 3;
        const int of = q * 32 + (lane & 31);
        const int k  = ks * 16 + (lane >> 5) * 8 + j;
        w1F[e] = f2bf(w1[k * 128 + of]);
    } else if (e < 18432) {
        const int i = e - 16384;    // w0F[q][lane][8]: k<4 = w0, k==4 = b0, else 0
        const int j = i & 7, lane = (i >> 3) & 63, q = (i >> 9) & 3;
        const int of = q * 32 + (lane & 31);
        const int k  = (lane >> 5) * 8 + j;
        unsigned short v = 0;
        if (k < 4)       v = f2bf(w0[k * 128 + of]);
        else if (k == 4) v = f2bf(b0[of]);
        w0F[i] = v;
    } else if (e < 51200) {
        const int i = e - 18432;           // W0p[kp][o] = sum_of w2[kp][of]*fw0[of][o]
        const int o = i & 255, kp = i >> 8;
        float v = 0.f;
        for (int of0 = 0; of0 < 128; of0 += 16) {
            float wa[16], wb[16];
            #pragma unroll
            for (int u = 0; u < 16; ++u) {
                wa[u] = w2[kp * 128 + of0 + u];
                wb[u] = fw0[(of0 + u) * 256 + o];
            }
            #pragma unroll
            for (int u = 0; u < 16; ++u)
                v = fmaf(wa[u], wb[u], v);
        }
        W0p[kp * 256 + o] = v;
    } else if (e < 51456) {
        const int o = e - 51200;           // c0p[o] = sum_of b2[of]*fw0[of][o]
        float v = 0.f;
        #pragma unroll 8
        for (int of = 0; of < 128; ++of)
            v = fmaf(b2[of], fw0[of * 256 + o], v);
        c0p[o] = v;
    }
}

// phi tile: 64 nodes, 4 waves = 4 of-quarters. h1 = 16KB LDS (64*128 ushort).
static __device__ __forceinline__ void phi_tile(
        int n0, int tid, unsigned short* __restrict__ h1,
        const float* __restrict__ x, const int* __restrict__ batch,
        const unsigned short* __restrict__ w0F,
        const unsigned short* __restrict__ w1F, const float* __restrict__ b1,
        float* __restrict__ P, float* __restrict__ cnts) {
    const int lane = tid & 63;
    const int q    = tid >> 6;
    const int l31  = lane & 31;
    const int h    = lane >> 5;

    const int gi = batch[n0 + lane];
    const int gp = __shfl_up(gi, 1);
    const unsigned long long mask = __ballot((lane == 0) || (gi != gp));

    f32x16 acc[2];

    // ---- layer 1 (swapped: A = w0F quarter fragment, B = x rows + 1-slot) ----
    {
        const short8 af = *reinterpret_cast<const short8*>(w0F + (q*64 + lane)*8);
        short8 bf[2];
        #pragma unroll
        for (int nt = 0; nt < 2; ++nt) {
            const float4 xv = *reinterpret_cast<const float4*>(
                x + (size_t)(n0 + nt*32 + l31) * 4);
            short8 v = (short8){0,0,0,0,0,0,0,0};
            if (h == 0) {
                v[0] = (short)f2bf(xv.x); v[1] = (short)f2bf(xv.y);
                v[2] = (short)f2bf(xv.z); v[3] = (short)f2bf(xv.w);
                v[4] = (short)0x3F80;     // bf16(1.0): picks up b0 row
            }
            bf[nt] = v;
        }
        acc[0] = (f32x16){}; acc[1] = (f32x16){};
        #pragma unroll
        for (int nt = 0; nt < 2; ++nt)
            acc[nt] = __builtin_amdgcn_mfma_f32_32x32x16_bf16(
                af, bf[nt], acc[nt], 0, 0, 0);
    }
    // ---- writeback h1: ReLU + bf16 only (bias already in acc) ----
    #pragma unroll
    for (int g4 = 0; g4 < 4; ++g4) {
        #pragma unroll
        for (int nt = 0; nt < 2; ++nt) {
            const int node = nt*32 + l31;
            const f32x16 A = acc[nt];
            ushort4 s;
            s.x = f2bf(fmaxf(A[g4*4+0], 0.f));
            s.y = f2bf(fmaxf(A[g4*4+1], 0.f));
            s.z = f2bf(fmaxf(A[g4*4+2], 0.f));
            s.w = f2bf(fmaxf(A[g4*4+3], 0.f));
            *reinterpret_cast<ushort4*>(&h1[swz(node, q*4 + g4) + h*4]) = s;
        }
    }
    __syncthreads();   // all quarters of h1 visible

    // ---- layer 2 (NORMAL: A = h1 node rows (full K=128), B = w1F of-quarter) ----
    acc[0] = (f32x16){}; acc[1] = (f32x16){};
    #pragma unroll
    for (int ks = 0; ks < 8; ++ks) {
        short8 a[2];
        #pragma unroll
        for (int mtn = 0; mtn < 2; ++mtn)
            a[mtn] = *reinterpret_cast<const short8*>(
                &h1[swz(mtn*32 + l31, ks*2 + h)]);
        const short8 bb = *reinterpret_cast<const short8*>(
            w1F + ((q*8 + ks)*64 + lane)*8);
        #pragma unroll
        for (int mtn = 0; mtn < 2; ++mtn)
            acc[mtn] = __builtin_amdgcn_mfma_f32_32x32x16_bf16(
                a[mtn], bb, acc[mtn], 0, 0, 0);
    }

    // ---- bias b1 + ReLU in f32 ----
    const float b1v = b1[q*32 + l31];
    #pragma unroll
    for (int mtn = 0; mtn < 2; ++mtn)
        #pragma unroll
        for (int r = 0; r < 16; ++r)
            acc[mtn][r] = fmaxf(acc[mtn][r] + b1v, 0.f);

    // ---- total sum over all 64 nodes ----
    float tot = 0.f;
    #pragma unroll
    for (int mtn = 0; mtn < 2; ++mtn) {
        const f32x16 A = acc[mtn];
        #pragma unroll
        for (int r = 0; r < 16; ++r) tot += A[r];
    }

    // ---- pooled segmented sum -> P[graph][of], plus node counts ----
    if (mask == 1ull) {
        float val = tot + __shfl_xor(tot, 32);
        if (h == 0)
            atomicAdd(P + (size_t)gi * 128 + q*32 + l31, val);
        if (tid == 0)
            atomicAdd(cnts + gi, 64.f);
    } else {
        unsigned long long rem = mask & (mask - 1);
        float below = 0.f;
        int s = 0;
        while (true) {
            const int e = rem ? (int)__builtin_ctzll(rem) : 64;
            const int grun = __shfl(gi, s);
            float run;
            if (e == 64) {
                run = tot - below;
            } else {
                float pref = 0.f;
                #pragma unroll
                for (int mtn = 0; mtn < 2; ++mtn) {
                    const f32x16 A = acc[mtn];
                    #pragma unroll
                    for (int r = 0; r < 16; ++r) {
                        const int node = mtn*32 + (r & 3) + 8*(r >> 2) + 4*h;
                        const float inc = (node < e) ? 1.f : 0.f;
                        pref = fmaf(A[r], inc, pref);
                    }
                }
                run = pref - below;
                below = pref;
            }
            const float val = run + __shfl_xor(run, 32);
            if (h == 0)
                atomicAdd(P + (size_t)grun * 128 + q*32 + l31, val);
            if (tid == 0)
                atomicAdd(cnts + grun, (float)(e - s));
            if (!rem) break;
            s = e;
            rem &= rem - 1;
        }
    }
}

// head chunk: 4 graphs. smemF = float LDS base (needs 4644 floats).
static __device__ __forceinline__ void head_chunk(
        int g0, int tid, float* __restrict__ smemF,
        const float* __restrict__ P, const float* __restrict__ cnts,
        const float* __restrict__ W0p, const float* __restrict__ c0p,
        const float* __restrict__ fb0,
        const float* __restrict__ fw1, const float* __restrict__ fb1,
        const float* __restrict__ fw2, const float* __restrict__ fb2,
        float* __restrict__ out) {
    float* gS   = smemF;               // 128*GS = 1536 floats
    float* h1T  = gS + 128 * GS;       // 256*GS = 3072 floats
    float* red  = h1T + 256 * GS;      // 4*8 = 32 floats
    float* cntS = red + 32;            // HG floats

    if (tid < HG) cntS[tid] = cnts[g0 + tid];
    {
        const int gr = tid >> 6, k0 = (tid & 63) * 2;
        const float2 v = *reinterpret_cast<const float2*>(
            P + (size_t)(g0 + gr) * 128 + k0);
        gS[(k0+0)*GS + gr] = v.x;
        gS[(k0+1)*GS + gr] = v.y;
    }
    __syncthreads();

    float a1[HG];
    #pragma unroll
    for (int i = 0; i < HG; ++i) a1[i] = 0.f;
    for (int k0 = 0; k0 < 128; k0 += 16) {
        float w[16];
        #pragma unroll
        for (int u = 0; u < 16; ++u)
            w[u] = W0p[(k0 + u) * 256 + tid];
        #pragma unroll
        for (int u = 0; u < 16; ++u) {
            const f32x4 v0 = *reinterpret_cast<const f32x4*>(&gS[(k0+u)*GS]);
            #pragma unroll
            for (int j = 0; j < 4; ++j)
                a1[j] = fmaf(v0[j], w[u], a1[j]);
        }
    }
    {
        const float bb = fb0[tid];
        const float cc = c0p[tid];
        f32x4 s0;
        #pragma unroll
        for (int j = 0; j < 4; ++j)
            s0[j] = fmaxf(fmaf(cntS[j], cc, a1[j]) + bb, 0.f);
        *reinterpret_cast<f32x4*>(&h1T[tid*GS]) = s0;
    }
    __syncthreads();

    float a2[HG];
    #pragma unroll
    for (int i = 0; i < HG; ++i) a2[i] = 0.f;
    for (int k0 = 0; k0 < 256; k0 += 16) {
        float w[16];
        #pragma unroll
        for (int u = 0; u < 16; ++u)
            w[u] = fw1[(k0 + u) * 256 + tid];
        #pragma unroll
        for (int u = 0; u < 16; ++u) {
            const f32x4 v0 = *reinterpret_cast<const f32x4*>(&h1T[(k0+u)*GS]);
            #pragma unroll
            for (int j = 0; j < 4; ++j)
                a2[j] = fmaf(v0[j], w[u], a2[j]);
        }
    }

    float p[2*HG];
    {
        const float bb  = fb1[tid];
        const float w2a = fw2[tid*2 + 0];
        const float w2b = fw2[tid*2 + 1];
        #pragma unroll
        for (int i = 0; i < HG; ++i) {
            const float h2 = fmaxf(a2[i] + bb, 0.f);
            p[i*2 + 0] = h2 * w2a;
            p[i*2 + 1] = h2 * w2b;
        }
    }
    #pragma unroll
    for (int i = 0; i < 2*HG; ++i) {
        float v = p[i];
        v += __shfl_xor(v, 32); v += __shfl_xor(v, 16); v += __shfl_xor(v, 8);
        v += __shfl_xor(v, 4);  v += __shfl_xor(v, 2);  v += __shfl_xor(v, 1);
        p[i] = v;
    }
    if ((tid & 63) == 0) {
        #pragma unroll
        for (int i = 0; i < 2*HG; ++i) red[(tid >> 6) * 8 + i] = p[i];
    }
    __syncthreads();
    if (tid < 2*HG)
        out[g0*2 + tid] = red[0*8 + tid] + red[1*8 + tid] + red[2*8 + tid]
                        + red[3*8 + tid] + fb2[tid & 1];
}

// ================= fused cooperative kernel =================================

__global__ __launch_bounds__(256, 4) void fused_kernel(
        const float* __restrict__ x, const int* __restrict__ batch,
        const float* __restrict__ w0, const float* __restrict__ b0,
        const float* __restrict__ w1, const float* __restrict__ b1,
        const float* __restrict__ w2, const float* __restrict__ fw0,
        const float* __restrict__ b2, const float* __restrict__ fb0,
        const float* __restrict__ fw1, const float* __restrict__ fb1,
        const float* __restrict__ fw2, const float* __restrict__ fb2,
        float* __restrict__ out,
        unsigned short* __restrict__ w0F, unsigned short* __restrict__ w1F,
        float* __restrict__ W0p, float* __restrict__ c0p,
        float* __restrict__ P, float* __restrict__ cnts) {
    // LDS overlay: phi h1 (16384 B) / head floats (18576 B) -> 18688 B
    __shared__ __align__(16) unsigned char smem[18688];
    const int tid = threadIdx.x;
    cg::grid_group grid = cg::this_grid();

    // ---- phase A: prep + zeroing (grid-strided, single pass at 1024x256) ----
    prep_body(blockIdx.x * 256 + tid, w0, b0, w1, w2, fw0, b2,
              w0F, w1F, W0p, c0p, P);

    grid.sync();

    // ---- phase B: phi over 8192 tiles, 8 per block (runtime loop) ----
    {
        unsigned short* h1 = reinterpret_cast<unsigned short*>(smem);
        for (int tile = blockIdx.x; tile < NNODES / 64; tile += gridDim.x) {
            phi_tile(tile * 64, tid, h1, x, batch, w0F, w1F, b1, P, cnts);
            __syncthreads();   // h1 reads drained before next tile's writeback
        }
    }

    grid.sync();

    // ---- phase C: head, one 4-graph chunk per block ----
    {
        float* smemF = reinterpret_cast<float*>(smem);
        for (int hb = blockIdx.x; hb < NGRAPHS / HG; hb += gridDim.x)
            head_chunk(hb * HG, tid, smemF, P, cnts, W0p, c0p, fb0,
                       fw1, fb1, fw2, fb2, out);
    }
}

// ================= standalone fallback kernels (R13 state) ==================

__global__ __launch_bounds__(256) void prep_weights(
        const float* __restrict__ w0, const float* __restrict__ b0,
        const float* __restrict__ w1,
        const float* __restrict__ w2, const float* __restrict__ fw0,
        const float* __restrict__ b2,
        unsigned short* __restrict__ w0F, unsigned short* __restrict__ w1F,
        float* __restrict__ W0p, float* __restrict__ c0p,
        float* __restrict__ Pz) {
    prep_body(blockIdx.x * 256 + threadIdx.x, w0, b0, w1, w2, fw0, b2,
              w0F, w1F, W0p, c0p, Pz);
}

__global__ __launch_bounds__(256, 6) void phi_kernel(
        const float* __restrict__ x, const int* __restrict__ batch,
        const unsigned short* __restrict__ w0F,
        const unsigned short* __restrict__ w1F, const float* __restrict__ b1,
        float* __restrict__ P, float* __restrict__ cnts) {
    __shared__ __align__(16) unsigned short h1[64 * 128];
    phi_tile(blockIdx.x * 64, threadIdx.x, h1, x, batch, w0F, w1F, b1, P, cnts);
}

__global__ __launch_bounds__(256, 4) void head_kernel(
        const float* __restrict__ P, const float* __restrict__ cnts,
        const float* __restrict__ W0p, const float* __restrict__ c0p,
        const float* __restrict__ fb0,
        const float* __restrict__ fw1, const float* __restrict__ fb1,
        const float* __restrict__ fw2, const float* __restrict__ fb2,
        float* __restrict__ out) {
    __shared__ __align__(16) float smemF[4644];
    head_chunk(blockIdx.x * HG, threadIdx.x, smemF, P, cnts, W0p, c0p, fb0,
               fw1, fb1, fw2, fb2, out);
}

// ================= launcher =================================================

extern "C" void kernel_launch(void* const* d_in, const int* in_sizes, int n_in,
                              void* d_out, int out_size, void* d_ws, size_t ws_size,
                              hipStream_t stream) {
    const float* x   = (const float*)d_in[0];
    // d_in[1] edge_index: mathematically dead (update() ignores aggr_out) — never read
    const int*   batch = (const int*)d_in[2];
    const float* w0  = (const float*)d_in[3];
    const float* b0  = (const float*)d_in[4];
    const float* w1  = (const float*)d_in[5];
    const float* b1  = (const float*)d_in[6];
    const float* w2  = (const float*)d_in[7];
    const float* b2  = (const float*)d_in[8];
    const float* fw0 = (const float*)d_in[9];
    const float* fb0 = (const float*)d_in[10];
    const float* fw1 = (const float*)d_in[11];
    const float* fb1 = (const float*)d_in[12];
    const float* fw2 = (const float*)d_in[13];
    const float* fb2 = (const float*)d_in[14];
    float* out = (float*)d_out;

    float* P    = (float*)d_ws;                       // 4096*128 f32 = 2 MB
    float* cnts = P + (size_t)NGRAPHS * 128;          // 4096 f32 = 16 KB
    unsigned short* w1F = (unsigned short*)(cnts + NGRAPHS);   // 32 KB
    unsigned short* w0F = w1F + 16384;                // 4 KB
    float* W0p = (float*)(w0F + 2048);                // 128*256 f32 = 128 KB
    float* c0p = W0p + 128 * 256;                     // 1 KB

    void* args[] = {
        (void*)&x, (void*)&batch,
        (void*)&w0, (void*)&b0, (void*)&w1, (void*)&b1, (void*)&w2,
        (void*)&fw0, (void*)&b2, (void*)&fb0, (void*)&fw1, (void*)&fb1,
        (void*)&fw2, (void*)&fb2, (void*)&out,
        (void*)&w0F, (void*)&w1F, (void*)&W0p, (void*)&c0p,
        (void*)&P, (void*)&cnts
    };
    hipError_t err = hipLaunchCooperativeKernel(
        reinterpret_cast<const void*>(fused_kernel),
        dim3(FGRID), dim3(256), args, 0, stream);

    if (err != hipSuccess) {
        // fallback: proven 3-kernel path (R13 state)
        prep_weights<<<516, 256, 0, stream>>>(w0, b0, w1, w2, fw0, b2,
                                              w0F, w1F, W0p, c0p, P);
        phi_kernel<<<NNODES / 64, 256, 0, stream>>>(x, batch, w0F, w1F, b1,
                                                    P, cnts);
        head_kernel<<<NGRAPHS / HG, 256, 0, stream>>>(P, cnts, W0p, c0p, fb0,
                                                      fw1, fb1, fw2, fb2, out);
    }
}

// Round 15
// 152.299 us; speedup vs baseline: 3.7396x; 3.7396x over previous
//
#include <hip/hip_runtime.h>
#include <hip/hip_bf16.h>

#define NNODES   524288
#define NGRAPHS  4096
#define HG       4     // head: graphs per block (1024 blocks, 4/CU)
#define GS       12    // head LDS row stride (floats), 16B-aligned rows

typedef __attribute__((ext_vector_type(8)))  short short8;
typedef __attribute__((ext_vector_type(4)))  float f32x4;
typedef __attribute__((ext_vector_type(16))) float f32x16;

static __device__ __forceinline__ unsigned short f2bf(float f) {
    __hip_bfloat16 h = __float2bfloat16(f);
    return *reinterpret_cast<unsigned short*>(&h);
}

// swizzled LDS offset (shorts): node-row 128 shorts, 16B chunks XOR-permuted
static __device__ __forceinline__ int swz(int node, int chunk) {
    return node * 128 + ((chunk ^ (node & 15)) << 3);
}

// ---- one-time prep ----
// zeroes P+cnts, builds w1F/w0F bf16 fragment layouts (w0F k=4 slot = b0:
// layer-1 MFMA computes x@w0 + b0 via the free K-padding), and folds phi
// layer-3 into the head: W0p = w2 @ fw0 (128x256), c0p = b2 @ fw0.
__global__ __launch_bounds__(256) void prep_weights(
        const float* __restrict__ w0, const float* __restrict__ b0,
        const float* __restrict__ w1,
        const float* __restrict__ w2, const float* __restrict__ fw0,
        const float* __restrict__ b2,
        unsigned short* __restrict__ w0F, unsigned short* __restrict__ w1F,
        float* __restrict__ W0p, float* __restrict__ c0p,
        float* __restrict__ Pz) {
    const int e = blockIdx.x * 256 + threadIdx.x;       // grid 516 -> e < 132096
    if (e < 132096)                                     // P (2MB) + cnts (16KB)
        reinterpret_cast<float4*>(Pz)[e] = make_float4(0.f, 0.f, 0.f, 0.f);
    if (e < 16384) {
        // w1F: of = q*32+(lane&31), k = ks*16+(lane>>5)*8+j
        const int j = e & 7, lane = (e >> 3) & 63, ks = (e >> 9) & 7, q = (e >> 12) & 3;
        const int of = q * 32 + (lane & 31);
        const int k  = ks * 16 + (lane >> 5) * 8 + j;
        w1F[e] = f2bf(w1[k * 128 + of]);
    } else if (e < 18432) {
        const int i = e - 16384;    // w0F[q][lane][8]: k<4 = w0, k==4 = b0, else 0
        const int j = i & 7, lane = (i >> 3) & 63, q = (i >> 9) & 3;
        const int of = q * 32 + (lane & 31);
        const int k  = (lane >> 5) * 8 + j;
        unsigned short v = 0;
        if (k < 4)       v = f2bf(w0[k * 128 + of]);
        else if (k == 4) v = f2bf(b0[of]);
        w0F[i] = v;
    } else if (e < 51200) {
        const int i = e - 18432;           // W0p[kp][o] = sum_of w2[kp][of]*fw0[of][o]
        const int o = i & 255, kp = i >> 8;
        float v = 0.f;
        for (int of0 = 0; of0 < 128; of0 += 16) {
            float wa[16], wb[16];
            #pragma unroll
            for (int u = 0; u < 16; ++u) {      // 32 independent loads in flight
                wa[u] = w2[kp * 128 + of0 + u];
                wb[u] = fw0[(of0 + u) * 256 + o];
            }
            #pragma unroll
            for (int u = 0; u < 16; ++u)
                v = fmaf(wa[u], wb[u], v);
        }
        W0p[kp * 256 + o] = v;
    } else if (e < 51456) {
        const int o = e - 51200;           // c0p[o] = sum_of b2[of]*fw0[of][o]
        float v = 0.f;
        #pragma unroll 8
        for (int of = 0; of < 128; ++of)
            v = fmaf(b2[of], fw0[of * 256 + o], v);
        c0p[o] = v;
    }
}

// ---- fused phi MLP (2 layers) + f32 segmented pooling ----
// Single 64-node tile, (256,6), in-loop w1F loads, prefix-diff epilogue.
// b0 folded into layer-1 MFMA (k=4 slot): writeback is relu+cvt only.
__global__ __launch_bounds__(256, 6) void phi_kernel(
        const float* __restrict__ x, const int* __restrict__ batch,
        const unsigned short* __restrict__ w0F,
        const unsigned short* __restrict__ w1F, const float* __restrict__ b1,
        float* __restrict__ P, float* __restrict__ cnts) {
    __shared__ __align__(16) unsigned short h1[64 * 128];   // 16 KB
    const int tid  = threadIdx.x;
    const int lane = tid & 63;
    const int q    = tid >> 6;        // of-quarter owner: of in [q*32, q*32+32)
    const int n0   = blockIdx.x * 64;
    const int l31  = lane & 31;
    const int h    = lane >> 5;

    // graph ids + run-start mask (identical in all 4 waves)
    const int gi = batch[n0 + lane];
    const int gp = __shfl_up(gi, 1);
    const unsigned long long mask = __ballot((lane == 0) || (gi != gp));

    f32x16 acc[2];

    // ---- layer 1 (swapped: A = w0F quarter fragment, B = x rows + 1-slot) ----
    // K=16: k<4 = x features, k=4 = 1.0 (bias row in w0F) -> acc = x@w0 + b0
    {
        const short8 af = *reinterpret_cast<const short8*>(w0F + (q*64 + lane)*8);
        short8 bf[2];
        #pragma unroll
        for (int nt = 0; nt < 2; ++nt) {
            const float4 xv = *reinterpret_cast<const float4*>(
                x + (size_t)(n0 + nt*32 + l31) * 4);
            short8 v = (short8){0,0,0,0,0,0,0,0};
            if (h == 0) {
                v[0] = (short)f2bf(xv.x); v[1] = (short)f2bf(xv.y);
                v[2] = (short)f2bf(xv.z); v[3] = (short)f2bf(xv.w);
                v[4] = (short)0x3F80;     // bf16(1.0): picks up b0 row
            }
            bf[nt] = v;
        }
        acc[0] = (f32x16){}; acc[1] = (f32x16){};
        #pragma unroll
        for (int nt = 0; nt < 2; ++nt)
            acc[nt] = __builtin_amdgcn_mfma_f32_32x32x16_bf16(
                af, bf[nt], acc[nt], 0, 0, 0);
    }
    // ---- writeback h1: ReLU + bf16 only (bias already in acc) ----
    #pragma unroll
    for (int g4 = 0; g4 < 4; ++g4) {
        #pragma unroll
        for (int nt = 0; nt < 2; ++nt) {
            const int node = nt*32 + l31;
            const f32x16 A = acc[nt];
            ushort4 s;
            s.x = f2bf(fmaxf(A[g4*4+0], 0.f));
            s.y = f2bf(fmaxf(A[g4*4+1], 0.f));
            s.z = f2bf(fmaxf(A[g4*4+2], 0.f));
            s.w = f2bf(fmaxf(A[g4*4+3], 0.f));
            *reinterpret_cast<ushort4*>(&h1[swz(node, q*4 + g4) + h*4]) = s;
        }
    }
    __syncthreads();   // all quarters of h1 visible

    // ---- layer 2 (NORMAL: A = h1 node rows (full K=128), B = w1F of-quarter) ----
    // C: col=of-local(l31), row=node -> pooling is register-local per lane.
    acc[0] = (f32x16){}; acc[1] = (f32x16){};
    #pragma unroll
    for (int ks = 0; ks < 8; ++ks) {
        short8 a[2];
        #pragma unroll
        for (int mtn = 0; mtn < 2; ++mtn)
            a[mtn] = *reinterpret_cast<const short8*>(
                &h1[swz(mtn*32 + l31, ks*2 + h)]);
        const short8 bb = *reinterpret_cast<const short8*>(
            w1F + ((q*8 + ks)*64 + lane)*8);
        #pragma unroll
        for (int mtn = 0; mtn < 2; ++mtn)
            acc[mtn] = __builtin_amdgcn_mfma_f32_32x32x16_bf16(
                a[mtn], bb, acc[mtn], 0, 0, 0);
    }

    // ---- bias b1 + ReLU in f32 (of = q*32+l31 fixed per lane) ----
    const float b1v = b1[q*32 + l31];
    #pragma unroll
    for (int mtn = 0; mtn < 2; ++mtn)
        #pragma unroll
        for (int r = 0; r < 16; ++r)
            acc[mtn][r] = fmaxf(acc[mtn][r] + b1v, 0.f);

    // ---- total sum over all 64 nodes (used by both paths) ----
    float tot = 0.f;
    #pragma unroll
    for (int mtn = 0; mtn < 2; ++mtn) {
        const f32x16 A = acc[mtn];
        #pragma unroll
        for (int r = 0; r < 16; ++r) tot += A[r];
    }

    // ---- pooled segmented sum -> P[graph][of], plus node counts ----
    if (mask == 1ull) {
        float val = tot + __shfl_xor(tot, 32);
        if (h == 0)
            atomicAdd(P + (size_t)gi * 128 + q*32 + l31, val);
        if (tid == 0)
            atomicAdd(cnts + gi, 64.f);
    } else {
        // prefix-difference: one single-compare pass per boundary; last run free
        unsigned long long rem = mask & (mask - 1);
        float below = 0.f;
        int s = 0;
        while (true) {
            const int e = rem ? (int)__builtin_ctzll(rem) : 64;
            const int grun = __shfl(gi, s);
            float run;
            if (e == 64) {
                run = tot - below;
            } else {
                float pref = 0.f;
                #pragma unroll
                for (int mtn = 0; mtn < 2; ++mtn) {
                    const f32x16 A = acc[mtn];
                    #pragma unroll
                    for (int r = 0; r < 16; ++r) {
                        const int node = mtn*32 + (r & 3) + 8*(r >> 2) + 4*h;
                        const float inc = (node < e) ? 1.f : 0.f;
                        pref = fmaf(A[r], inc, pref);
                    }
                }
                run = pref - below;
                below = pref;
            }
            const float val = run + __shfl_xor(run, 32);
            if (h == 0)
                atomicAdd(P + (size_t)grun * 128 + q*32 + l31, val);
            if (tid == 0)
                atomicAdd(cnts + grun, (float)(e - s));
            if (!rem) break;
            s = e;
            rem &= rem - 1;
        }
    }
}

// ---- F head: 4 graphs/block, 1024 blocks (4/CU), 16-deep weight batching ----
// a1 = P@W0p + cnt*c0p + fb0 (folded phi-L3), relu; a2 = h1@fw1 + fb1, relu;
// out = h2@fw2 + fb2 via shuffle-reduce.
__global__ __launch_bounds__(256, 4) void head_kernel(
        const float* __restrict__ P, const float* __restrict__ cnts,
        const float* __restrict__ W0p, const float* __restrict__ c0p,
        const float* __restrict__ fb0,
        const float* __restrict__ fw1, const float* __restrict__ fb1,
        const float* __restrict__ fw2, const float* __restrict__ fb2,
        float* __restrict__ out) {
    __shared__ float gS[128 * GS];
    __shared__ float h1T[256 * GS];
    __shared__ float red[4][8];
    __shared__ float cntS[HG];
    const int tid = threadIdx.x;
    const int g0  = blockIdx.x * HG;

    if (tid < HG) cntS[tid] = cnts[g0 + tid];
    {
        const int gr = tid >> 6, k0 = (tid & 63) * 2;
        const float2 v = *reinterpret_cast<const float2*>(
            P + (size_t)(g0 + gr) * 128 + k0);
        gS[(k0+0)*GS + gr] = v.x;
        gS[(k0+1)*GS + gr] = v.y;
    }
    __syncthreads();

    // ---- layer 1: a1[g] = sum_k gS[k][g] * W0p[k][tid], 16-deep load batches ----
    float a1[HG];
    #pragma unroll
    for (int i = 0; i < HG; ++i) a1[i] = 0.f;
    for (int k0 = 0; k0 < 128; k0 += 16) {
        float w[16];
        #pragma unroll
        for (int u = 0; u < 16; ++u)
            w[u] = W0p[(k0 + u) * 256 + tid];       // 16 independent coalesced loads
        #pragma unroll
        for (int u = 0; u < 16; ++u) {
            const f32x4 v0 = *reinterpret_cast<const f32x4*>(&gS[(k0+u)*GS]);
            #pragma unroll
            for (int j = 0; j < 4; ++j)
                a1[j] = fmaf(v0[j], w[u], a1[j]);
        }
    }
    {
        const float bb = fb0[tid];
        const float cc = c0p[tid];
        f32x4 s0;
        #pragma unroll
        for (int j = 0; j < 4; ++j)
            s0[j] = fmaxf(fmaf(cntS[j], cc, a1[j]) + bb, 0.f);
        *reinterpret_cast<f32x4*>(&h1T[tid*GS]) = s0;
    }
    __syncthreads();

    // ---- layer 2: a2[g] = sum_k h1T[k][g] * fw1[k][tid], 16-deep batches ----
    float a2[HG];
    #pragma unroll
    for (int i = 0; i < HG; ++i) a2[i] = 0.f;
    for (int k0 = 0; k0 < 256; k0 += 16) {
        float w[16];
        #pragma unroll
        for (int u = 0; u < 16; ++u)
            w[u] = fw1[(k0 + u) * 256 + tid];
        #pragma unroll
        for (int u = 0; u < 16; ++u) {
            const f32x4 v0 = *reinterpret_cast<const f32x4*>(&h1T[(k0+u)*GS]);
            #pragma unroll
            for (int j = 0; j < 4; ++j)
                a2[j] = fmaf(v0[j], w[u], a2[j]);
        }
    }

    // ---- layer 3: thread-local partials over o=tid, shuffle-reduce ----
    float p[8];
    {
        const float bb  = fb1[tid];
        const float w2a = fw2[tid*2 + 0];
        const float w2b = fw2[tid*2 + 1];
        #pragma unroll
        for (int i = 0; i < HG; ++i) {
            const float h2 = fmaxf(a2[i] + bb, 0.f);
            p[i*2 + 0] = h2 * w2a;
            p[i*2 + 1] = h2 * w2b;
        }
    }
    #pragma unroll
    for (int i = 0; i < 8; ++i) {
        float v = p[i];
        v += __shfl_xor(v, 32); v += __shfl_xor(v, 16); v += __shfl_xor(v, 8);
        v += __shfl_xor(v, 4);  v += __shfl_xor(v, 2);  v += __shfl_xor(v, 1);
        p[i] = v;
    }
    if ((tid & 63) == 0) {
        #pragma unroll
        for (int i = 0; i < 8; ++i) red[tid >> 6][i] = p[i];
    }
    __syncthreads();
    if (tid < 8)
        out[g0*2 + tid] = red[0][tid] + red[1][tid] + red[2][tid] + red[3][tid]
                        + fb2[tid & 1];
}

extern "C" void kernel_launch(void* const* d_in, const int* in_sizes, int n_in,
                              void* d_out, int out_size, void* d_ws, size_t ws_size,
                              hipStream_t stream) {
    const float* x   = (const float*)d_in[0];
    // d_in[1] edge_index: mathematically dead (update() ignores aggr_out) — never read
    const int*   batch = (const int*)d_in[2];
    const float* w0  = (const float*)d_in[3];
    const float* b0  = (const float*)d_in[4];
    const float* w1  = (const float*)d_in[5];
    const float* b1  = (const float*)d_in[6];
    const float* w2  = (const float*)d_in[7];
    const float* b2  = (const float*)d_in[8];
    const float* fw0 = (const float*)d_in[9];
    const float* fb0 = (const float*)d_in[10];
    const float* fw1 = (const float*)d_in[11];
    const float* fb1 = (const float*)d_in[12];
    const float* fw2 = (const float*)d_in[13];
    const float* fb2 = (const float*)d_in[14];
    float* out = (float*)d_out;

    float* P    = (float*)d_ws;                       // 4096*128 f32 = 2 MB
    float* cnts = P + (size_t)NGRAPHS * 128;          // 4096 f32 = 16 KB
    unsigned short* w1F = (unsigned short*)(cnts + NGRAPHS);   // 32 KB
    unsigned short* w0F = w1F + 16384;                // 4 KB
    float* W0p = (float*)(w0F + 2048);                // 128*256 f32 = 128 KB
    float* c0p = W0p + 128 * 256;                     // 1 KB

    // prep zeroes P+cnts (516*256 = 132096 float4) and builds all weight forms
    prep_weights<<<516, 256, 0, stream>>>(w0, b0, w1, w2, fw0, b2,
                                          w0F, w1F, W0p, c0p, P);
    phi_kernel<<<NNODES / 64, 256, 0, stream>>>(x, batch, w0F, w1F, b1, P, cnts);
    head_kernel<<<NGRAPHS / HG, 256, 0, stream>>>(P, cnts, W0p, c0p, fb0,
                                                  fw1, fb1, fw2, fb2, out);
}